// Round 10
// baseline (3120.029 us; speedup 1.0000x reference)
//
#include <hip/hip_runtime.h>
#include <math.h>

constexpr int B = 2;
constexpr int N = 10000;
constexpr int K = 10;
constexpr int NK = N * K;
constexpr float NEG = 0.2f;
constexpr float BN_EPS = 1e-5f;
constexpr int SB = 64;   // stats partial blocks per channel
constexpr int JS = 8;    // knn j-range splits

#define DEV __device__ __forceinline__

// ---------------- squared norms ----------------
__global__ void __launch_bounds__(256, 4)
xx_kernel(const float* __restrict__ x, long bstride, int C,
          float* __restrict__ xx) {
  int n = blockIdx.x * 256 + threadIdx.x;
  int b = blockIdx.y;
  if (n >= N) return;
  const float* xb = x + (long)b * bstride;
  float s = 0.f;
  for (int c = 0; c < C; ++c) { float v = xb[(long)c * N + n]; s += v * v; }
  xx[b * N + n] = s;
}

// ---------------- u64 packed key: (monotone f32 bits)<<32 | j ----------------
DEV unsigned int fkey(float d) {
  unsigned int b = __float_as_uint(d);
  return b ^ (((unsigned int)((int)b >> 31)) | 0x80000000u);
}
DEV unsigned long long pack_key(float d, unsigned int j) {
  return ((unsigned long long)fkey(d) << 32) | j;
}
DEV void topk_u64(unsigned long long (&best)[K], unsigned long long key) {
#pragma unroll
  for (int s = 0; s < K; ++s) {
    unsigned long long b = best[s];
    bool lt = key < b;
    best[s] = lt ? key : b;
    key = lt ? b : key;
  }
}
constexpr unsigned long long KEY_MAX = 0xFFFFFFFFFFFFFFFFull;

// ---------------- knn partial for C=3 (cheap, per-thread query) ----------------
template<int C, int TJ, int PAD>
__global__ void __launch_bounds__(256, 4)
knn_partial_kernel(const float* __restrict__ x, long bstride,
                   const float* __restrict__ xx,
                   unsigned long long* __restrict__ pk) {
  __shared__ __align__(16) float sx[TJ][PAD];
  __shared__ float sxx[TJ];
  int b = blockIdx.z;
  int js = blockIdx.y;
  int q = blockIdx.x * 256 + threadIdx.x;
  bool valid = q < N;
  const int CH = (N + JS - 1) / JS;
  int jbeg = js * CH;
  int jend = min(N, jbeg + CH);
  const float* xb = x + (long)b * bstride;
  float xi[C];
  float xxi = 0.f;
  if (valid) {
#pragma unroll
    for (int c = 0; c < C; ++c) xi[c] = xb[(long)c * N + q];
    xxi = xx[b * N + q];
  }
  unsigned long long best[K];
#pragma unroll
  for (int k = 0; k < K; ++k) best[k] = KEY_MAX;

  for (int j0 = jbeg; j0 < jend; j0 += TJ) {
    int cnt = min(TJ, jend - j0);
    __syncthreads();
    for (int e = threadIdx.x; e < C * TJ; e += 256) {
      int tj = e & (TJ - 1);
      int c = e / TJ;
      sx[tj][c] = (tj < cnt) ? xb[(long)c * N + j0 + tj] : 0.f;
    }
    for (int e = threadIdx.x; e < TJ; e += 256)
      sxx[e] = (e < cnt) ? xx[b * N + j0 + e] : 0.f;
    __syncthreads();
    if (!valid) continue;
    for (int tj = 0; tj < cnt; ++tj) {
      float dot = 0.f;
#pragma unroll
      for (int c = 0; c < C; ++c) dot += xi[c] * sx[tj][c];
      float d = xxi - 2.f * dot + sxx[tj];
      int j = j0 + tj;
      if (j != q) {
        unsigned long long key = pack_key(d, (unsigned int)j);
        if (key < best[K - 1]) topk_u64(best, key);
      }
    }
  }
  if (valid) {
    long base = ((long)(b * N + q) * JS + js) * K;
#pragma unroll
    for (int k = 0; k < K; ++k) pk[base + k] = best[k];
  }
}

// ---------------- knn C=64: tiled distance-GEMM + fused top-k ----------------
// R10: J-tile 128, per-thread 4q x 8j (acc[4][8], R8-GEMM-proven shape).
// LDS 1.125 B/FMA (was 2). 52,992 B -> 3 blocks/CU. (256,3): cap ~168, ~115 live.
// Distances -> D[j][q] (lane-stride-1 scan). Float-bits prefilter before u64 insert.
__global__ void __launch_bounds__(256, 3)
knn64_tiled_kernel(const float* __restrict__ x, long bstride,
                   const float* __restrict__ xx,
                   unsigned long long* __restrict__ pk) {
  __shared__ __align__(16) float smem[4352 + 8704 + 192];
  float* Qt = smem;                  // [c][q] pad 68
  float* JD = smem + 4352;           // [c][j] pad 132 (compute); D[j][q] pad 68 (scan)
  float* xxq = smem + 4352 + 8704;
  float* xxj = xxq + 64;
  int b = blockIdx.z, js = blockIdx.y, qt = blockIdx.x;
  int t = threadIdx.x;
  const float* xb = x + (long)b * bstride;
  const float* xxb = xx + b * N;
  int q0 = qt * 64;
#pragma unroll
  for (int r = 0; r < 16; ++r) {
    int e = t + r * 256;
    int q = e & 63, c = e >> 6;
    int qg = q0 + q;
    Qt[c * 68 + q] = (qg < N) ? xb[(long)c * N + qg] : 0.f;
  }
  if (t < 64) xxq[t] = (q0 + t < N) ? xxb[q0 + t] : 0.f;

  const int CH = N / JS;               // 1250
  int jbeg = js * CH, jend = jbeg + CH;
  int tx = t & 15, ty = t >> 4;        // compute coords: q-group tx (4q), j-group ty (8j)
  int sq = t & 63, quarter = t >> 6;   // scan coords

  unsigned long long best[K];
#pragma unroll
  for (int k = 0; k < K; ++k) best[k] = KEY_MAX;

  for (int jb = jbeg; jb < jend; jb += 128) {
    __syncthreads();  // previous scan done before overwriting JD
    // load J tile (128 j x 64 c), [c][j] pad 132
#pragma unroll
    for (int r = 0; r < 32; ++r) {
      int e = t + r * 256;
      int j = e & 127, c = e >> 7;
      int jg = jb + j;
      JD[c * 132 + j] = (jg < jend) ? xb[(long)c * N + jg] : 0.f;
    }
    if (t < 128) xxj[t] = (jb + t < jend) ? xxb[jb + t] : 3.4e38f;
    __syncthreads();

    float acc[4][8] = {};
#pragma unroll 4
    for (int c = 0; c < 64; ++c) {
      float4 aq = *(const float4*)&Qt[c * 68 + tx * 4];
      float4 b0 = *(const float4*)&JD[c * 132 + ty * 8];
      float4 b1 = *(const float4*)&JD[c * 132 + ty * 8 + 4];
      float av[4] = {aq.x, aq.y, aq.z, aq.w};
      float bv[8] = {b0.x, b0.y, b0.z, b0.w, b1.x, b1.y, b1.z, b1.w};
#pragma unroll
      for (int i = 0; i < 4; ++i)
#pragma unroll
        for (int jj = 0; jj < 8; ++jj) acc[i][jj] += av[i] * bv[jj];
    }
    __syncthreads();  // all reads of JD done before D overwrite

    // distances (with self-exclusion) -> D[j][q] pad 68
    float4 xj0 = *(const float4*)&xxj[ty * 8];
    float4 xj1 = *(const float4*)&xxj[ty * 8 + 4];
    float xjv[8] = {xj0.x, xj0.y, xj0.z, xj0.w, xj1.x, xj1.y, xj1.z, xj1.w};
    int selbase = q0 + tx * 4 - jb - ty * 8;   // (q - j) offset
    float d4[4][8];
#pragma unroll
    for (int i = 0; i < 4; ++i) {
      float xq = xxq[tx * 4 + i];
#pragma unroll
      for (int jj = 0; jj < 8; ++jj) {
        float dv = xq - 2.f * acc[i][jj] + xjv[jj];
        d4[i][jj] = (selbase + i == jj) ? 3.4e38f : dv;
      }
    }
#pragma unroll
    for (int jj = 0; jj < 8; ++jj) {
      float4 sv = make_float4(d4[0][jj], d4[1][jj], d4[2][jj], d4[3][jj]);
      *(float4*)&JD[(ty * 8 + jj) * 68 + tx * 4] = sv;
    }
    __syncthreads();

    // scan: thread owns query sq, j sub-range [quarter*32, quarter*32+32)
    // D[jl][sq]: lane-stride-1, conflict-free. Float-bits prefilter (exact, ties kept).
#pragma unroll 4
    for (int jj = 0; jj < 32; ++jj) {
      int jl = quarter * 32 + jj;
      float dv = JD[jl * 68 + sq];
      unsigned int hi = fkey(dv);
      if (hi <= (unsigned int)(best[K - 1] >> 32)) {
        unsigned long long key =
            ((unsigned long long)hi << 32) | (unsigned int)(jb + jl);
        if (key < best[K - 1]) topk_u64(best, key);
      }
    }
  }
  __syncthreads();
  // in-block merge across the 4 quarters
  unsigned long long* mb = (unsigned long long*)smem;
#pragma unroll
  for (int k = 0; k < K; ++k) mb[(sq * 4 + quarter) * K + k] = best[k];
  __syncthreads();
  if (t < 64 && q0 + t < N) {
    unsigned long long fb[K];
#pragma unroll
    for (int k = 0; k < K; ++k) fb[k] = KEY_MAX;
    for (int s = 0; s < 4; ++s)
#pragma unroll
      for (int k = 0; k < K; ++k) {
        unsigned long long key = mb[(t * 4 + s) * K + k];
        if (key < fb[K - 1]) topk_u64(fb, key);
      }
    long base = ((long)(b * N + q0 + t) * JS + js) * K;
#pragma unroll
    for (int k = 0; k < K; ++k) pk[base + k] = fb[k];
  }
}

// ---------------- knn merge ----------------
__global__ void __launch_bounds__(256, 4)
knn_merge_kernel(const unsigned long long* __restrict__ pk, int* __restrict__ idx) {
  int t = blockIdx.x * 256 + threadIdx.x;
  if (t >= B * N) return;
  unsigned long long best[K];
#pragma unroll
  for (int k = 0; k < K; ++k) best[k] = KEY_MAX;
  for (int s = 0; s < JS; ++s) {
    long base = ((long)t * JS + s) * K;
#pragma unroll
    for (int k = 0; k < K; ++k) {
      unsigned long long key = pk[base + k];
      if (key < best[K - 1]) topk_u64(best, key);
    }
  }
#pragma unroll
  for (int k = 0; k < K; ++k)
    idx[(long)t * K + k] = (int)(best[k] & 0xFFFFFFFFull);
}

// ---------------- templated tiled SGEMM ----------------
// MODE 0: plain X.  MODE 1: X staged through lrelu(x*scale[c]+shift[c]).
// MODE 2: X = lrelu(scale[c]*(yn[c][idx[m]] + yc[c][m/K]) + shift[c])  (gather+norm).
template<int MODE>
__global__ void __launch_bounds__(256, 2)
gemm_t_kernel(const float* __restrict__ W, int Wld,
              const float* __restrict__ X, long xbstride,
              const float* __restrict__ yc,
              const int* __restrict__ idx,
              const float* __restrict__ scale, const float* __restrict__ shift,
              float* __restrict__ Y, const float* __restrict__ bias,
              int Co, int Cin, int M) {
  __shared__ __align__(16) float Wt[16][64];
  __shared__ __align__(16) float Xt[16][128];
  __shared__ int jn_s[128];
  __shared__ int nn_s[128];
  int b = blockIdx.z;
  int m0 = blockIdx.x * 128;
  int o0 = blockIdx.y * 64;
  int t = threadIdx.x;
  int tx = t & 15, ty = t >> 4;
  if constexpr (MODE == 2) {
    if (t < 128) {
      int m = m0 + t;
      int n = 0, j = 0;
      if (m < M) { n = m / K; j = idx[(long)b * N * K + m]; }
      nn_s[t] = n; jn_s[t] = j;
    }
    __syncthreads();
  }
  float acc[4][8] = {};
  for (int c0 = 0; c0 < Cin; c0 += 16) {
#pragma unroll
    for (int r = 0; r < 4; ++r) {
      int e = t + r * 256;
      int o = e & 63, kc = e >> 6;
      int oo = o0 + o, cc = c0 + kc;
      Wt[kc][o] = (oo < Co && cc < Cin) ? W[(long)oo * Wld + cc] : 0.f;
    }
    {
      int kc = t >> 4, ms = (t & 15) * 8;
      int cc = c0 + kc;
      int mm = m0 + ms;
      float xv[8];
      if constexpr (MODE == 2) {
        const float* ynr = X + ((long)b * 64 + cc) * N;
        const float* ycr = yc + ((long)b * 64 + cc) * N;
        float sc = scale[cc], sh = shift[cc];
#pragma unroll
        for (int r = 0; r < 8; ++r) {
          int m = mm + r;
          float v = 0.f;
          if (m < M) {
            v = ynr[jn_s[ms + r]] + ycr[nn_s[ms + r]];
            v = v * sc + sh;
            v = v >= 0.f ? v : NEG * v;
          }
          xv[r] = v;
        }
      } else {
        bool okc = cc < Cin;
        const float* Xr = X + (long)b * xbstride + (long)cc * M;
        if (okc && mm + 8 <= M) {
          float4 a0 = *(const float4*)&Xr[mm];
          float4 a1 = *(const float4*)&Xr[mm + 4];
          xv[0] = a0.x; xv[1] = a0.y; xv[2] = a0.z; xv[3] = a0.w;
          xv[4] = a1.x; xv[5] = a1.y; xv[6] = a1.z; xv[7] = a1.w;
        } else {
#pragma unroll
          for (int r = 0; r < 8; ++r)
            xv[r] = (okc && mm + r < M) ? Xr[mm + r] : 0.f;
        }
        if constexpr (MODE == 1) {
          float sc = okc ? scale[cc] : 0.f;
          float sh = okc ? shift[cc] : 0.f;
#pragma unroll
          for (int r = 0; r < 8; ++r) {
            float v = xv[r] * sc + sh;
            xv[r] = v >= 0.f ? v : NEG * v;
          }
        }
      }
      *(float4*)&Xt[kc][ms] = make_float4(xv[0], xv[1], xv[2], xv[3]);
      *(float4*)&Xt[kc][ms + 4] = make_float4(xv[4], xv[5], xv[6], xv[7]);
    }
    __syncthreads();
#pragma unroll
    for (int kc = 0; kc < 16; ++kc) {
      float4 a = *(const float4*)&Wt[kc][ty * 4];
      float4 x0 = *(const float4*)&Xt[kc][tx * 4];
      float4 x1 = *(const float4*)&Xt[kc][64 + tx * 4];
      float av[4] = {a.x, a.y, a.z, a.w};
      float xr[8] = {x0.x, x0.y, x0.z, x0.w, x1.x, x1.y, x1.z, x1.w};
#pragma unroll
      for (int i = 0; i < 4; ++i)
#pragma unroll
        for (int j = 0; j < 8; ++j) acc[i][j] += av[i] * xr[j];
    }
    __syncthreads();
  }
#pragma unroll
  for (int i = 0; i < 4; ++i) {
    int oo = o0 + ty * 4 + i;
    if (oo >= Co) continue;
    float bv = bias ? bias[b * Co + oo] : 0.f;
    long ybase = ((long)b * Co + oo) * M;
    int mlo = m0 + tx * 4, mhi = m0 + 64 + tx * 4;
    if (mlo + 4 <= M) {
      float4 v = make_float4(acc[i][0] + bv, acc[i][1] + bv,
                             acc[i][2] + bv, acc[i][3] + bv);
      *(float4*)&Y[ybase + mlo] = v;
    } else {
#pragma unroll
      for (int j = 0; j < 4; ++j)
        if (mlo + j < M) Y[ybase + mlo + j] = acc[i][j] + bv;
    }
    if (mhi + 4 <= M) {
      float4 v = make_float4(acc[i][4] + bv, acc[i][5] + bv,
                             acc[i][6] + bv, acc[i][7] + bv);
      *(float4*)&Y[ybase + mhi] = v;
    } else {
#pragma unroll
      for (int j = 0; j < 4; ++j)
        if (mhi + j < M) Y[ybase + mhi + j] = acc[i][j + 4] + bv;
    }
  }
}

// ---------------- wmod[o][c] = W[o][Ch+c] - W[o][c] ----------------
__global__ void wdiff_kernel(const float* __restrict__ W, int Wld, int Ch, int Co,
                             float* __restrict__ wmod) {
  int e = blockIdx.x * 256 + threadIdx.x;
  if (e < Co * Ch) {
    int o = e / Ch, c = e % Ch;
    wmod[e] = W[o * Wld + Ch + c] - W[o * Wld + c];
  }
}

// ---------------- stats over materialized tensor ----------------
__global__ void __launch_bounds__(256, 4)
stats_kernel(const float* __restrict__ X, int C, int M,
             float* __restrict__ psum, float* __restrict__ psq) {
  int c = blockIdx.x, s = blockIdx.y;
  float sum = 0.f, sq = 0.f;
  for (int b = 0; b < B; ++b) {
    const float* p = X + ((long)b * C + c) * M;
    for (int m = s * 256 + threadIdx.x; m < M; m += SB * 256) {
      float v = p[m];
      sum += v; sq += v * v;
    }
  }
#pragma unroll
  for (int off = 32; off; off >>= 1) {
    sum += __shfl_down(sum, off);
    sq += __shfl_down(sq, off);
  }
  __shared__ float ls[8];
  int wid = threadIdx.x >> 6;
  if ((threadIdx.x & 63) == 0) { ls[wid] = sum; ls[4 + wid] = sq; }
  __syncthreads();
  if (threadIdx.x == 0) {
    psum[c * SB + s] = ls[0] + ls[1] + ls[2] + ls[3];
    psq[c * SB + s] = ls[4] + ls[5] + ls[6] + ls[7];
  }
}

// ---------------- stats over gathered edge tensor (on the fly) ----------------
__global__ void __launch_bounds__(256, 4)
stats_g_kernel(const float* __restrict__ yn, const float* __restrict__ yc,
               const int* __restrict__ idx,
               float* __restrict__ psum, float* __restrict__ psq) {
  int c = blockIdx.x, s = blockIdx.y;
  float sum = 0.f, sq = 0.f;
  for (int b = 0; b < B; ++b) {
    const float* ynr = yn + ((long)b * 64 + c) * N;
    const float* ycr = yc + ((long)b * 64 + c) * N;
    const int* ib = idx + (long)b * N * K;
    for (int m = s * 256 + threadIdx.x; m < NK; m += SB * 256) {
      int n = m / K;
      float v = ynr[ib[m]] + ycr[n];
      sum += v; sq += v * v;
    }
  }
#pragma unroll
  for (int off = 32; off; off >>= 1) {
    sum += __shfl_down(sum, off);
    sq += __shfl_down(sq, off);
  }
  __shared__ float ls[8];
  int wid = threadIdx.x >> 6;
  if ((threadIdx.x & 63) == 0) { ls[wid] = sum; ls[4 + wid] = sq; }
  __syncthreads();
  if (threadIdx.x == 0) {
    psum[c * SB + s] = ls[0] + ls[1] + ls[2] + ls[3];
    psq[c * SB + s] = ls[4] + ls[5] + ls[6] + ls[7];
  }
}

__global__ void finalize_kernel(const float* __restrict__ psum, const float* __restrict__ psq,
                                const float* __restrict__ g, const float* __restrict__ bb,
                                float* __restrict__ scale, float* __restrict__ shift,
                                int C, float inv_n) {
  int c = blockIdx.x * 256 + threadIdx.x;
  if (c >= C) return;
  float s = 0.f, q = 0.f;
  for (int i = 0; i < SB; ++i) { s += psum[c * SB + i]; q += psq[c * SB + i]; }
  float mean = s * inv_n;
  float var = q * inv_n - mean * mean;
  float sc = g[c] * rsqrtf(var + BN_EPS);
  scale[c] = sc;
  shift[c] = bb[c] - mean * sc;
}

// ---------------- fused norm+lrelu+max-over-K (materialized Z) ----------------
__global__ void __launch_bounds__(256, 4)
norm_maxk_kernel(const float* __restrict__ Z, const float* __restrict__ scale,
                 const float* __restrict__ shift, float* __restrict__ xc, int coff) {
  long e = (long)blockIdx.x * 256 + threadIdx.x;
  if (e >= (long)B * 64 * N) return;
  int n = (int)(e % N);
  long t = e / N;
  int o = (int)(t % 64);
  int b = (int)(t / 64);
  const float* p = Z + (((long)(b * 64 + o) * N) + n) * K;
  float sc = scale[o], sh = shift[o];
  float m = -3.4e38f;
#pragma unroll
  for (int k = 0; k < K; ++k) {
    float v = p[k] * sc + sh;
    v = v >= 0.f ? v : NEG * v;
    m = fmaxf(m, v);
  }
  xc[((long)b * 192 + coff + o) * N + n] = m;
}

// ---------------- fused gather+norm+lrelu+max-over-K ----------------
__global__ void __launch_bounds__(256, 4)
norm_maxk_g_kernel(const float* __restrict__ yn, const float* __restrict__ yc,
                   const int* __restrict__ idx,
                   const float* __restrict__ scale, const float* __restrict__ shift,
                   float* __restrict__ xc, int coff) {
  long e = (long)blockIdx.x * 256 + threadIdx.x;
  if (e >= (long)B * 64 * N) return;
  int n = (int)(e % N);
  long t = e / N;
  int o = (int)(t % 64);
  int b = (int)(t / 64);
  const int* ib = idx + ((long)b * N + n) * K;
  const float* ynr = yn + ((long)b * 64 + o) * N;
  float ycv = yc[((long)b * 64 + o) * N + n];
  float sc = scale[o], sh = shift[o];
  float m = -3.4e38f;
#pragma unroll
  for (int k = 0; k < K; ++k) {
    float v = (ynr[ib[k]] + ycv) * sc + sh;
    v = v >= 0.f ? v : NEG * v;
    m = fmaxf(m, v);
  }
  xc[((long)b * 192 + coff + o) * N + n] = m;
}

// ---------------- fused norm+lrelu+max over N (z5 -> glob[0:1024]) ----------------
__global__ void __launch_bounds__(256, 4)
norm_gmax_kernel(const float* __restrict__ Z5, const float* __restrict__ scale,
                 const float* __restrict__ shift, float* __restrict__ glob) {
  int r = blockIdx.x;  // B*1024
  int b = r >> 10, o = r & 1023;
  const float* p = Z5 + (long)r * N;
  float sc = scale[o], sh = shift[o];
  float m = -3.4e38f;
  for (int n = threadIdx.x; n < N; n += 256) {
    float v = p[n] * sc + sh;
    v = v >= 0.f ? v : NEG * v;
    m = fmaxf(m, v);
  }
#pragma unroll
  for (int off = 32; off; off >>= 1) m = fmaxf(m, __shfl_down(m, off));
  __shared__ float ls[4];
  int wid = threadIdx.x >> 6;
  if ((threadIdx.x & 63) == 0) ls[wid] = m;
  __syncthreads();
  if (threadIdx.x == 0)
    glob[b * 1088 + o] = fmaxf(fmaxf(ls[0], ls[1]), fmaxf(ls[2], ls[3]));
}

// ---------------- label branch (tiny) ----------------
__global__ void lfeat_kernel(const float* __restrict__ label, const float* __restrict__ W6,
                             const float* __restrict__ g6, const float* __restrict__ b6,
                             float* __restrict__ glob) {
  int o = threadIdx.x;
  if (o >= 64) return;
  float v[B];
  for (int b = 0; b < B; ++b) {
    float s = 0.f;
    for (int c = 0; c < 16; ++c) s += W6[o * 16 + c] * label[b * 16 + c];
    v[b] = s;
  }
  float mean = 0.f;
  for (int b = 0; b < B; ++b) mean += v[b];
  mean *= (1.f / B);
  float var = 0.f;
  for (int b = 0; b < B; ++b) var += (v[b] - mean) * (v[b] - mean);
  var *= (1.f / B);
  float sc = g6[o] * rsqrtf(var + BN_EPS);
  for (int b = 0; b < B; ++b) {
    float t = (v[b] - mean) * sc + b6[o];
    glob[b * 1088 + 1024 + o] = t >= 0.f ? t : NEG * t;
  }
}

// ---------------- bias0[b][o] = sum_c P0[o][192+c] * glob[b][c] ----------------
__global__ void __launch_bounds__(256, 4)
bias0_kernel(const float* __restrict__ P0, const float* __restrict__ glob,
             float* __restrict__ bias0) {
  int t = blockIdx.x * 256 + threadIdx.x;
  if (t >= B * 256) return;
  int b = t >> 8, o = t & 255;
  float s = 0.f;
  for (int c = 0; c < 1088; ++c) s += P0[o * 1280 + 192 + c] * glob[b * 1088 + c];
  bias0[b * 256 + o] = s;
}

extern "C" void kernel_launch(void* const* d_in, const int* in_sizes, int n_in,
                              void* d_out, int out_size, void* d_ws, size_t ws_size,
                              hipStream_t stream) {
  const float* pts = (const float*)d_in[0];
  const float* label = (const float*)d_in[1];
  const float* Wt7[7]; const float* gt[7]; const float* bt[7];
  for (int i = 0; i < 7; ++i) {
    Wt7[i] = (const float*)d_in[2 + 3 * i];
    gt[i] = (const float*)d_in[3 + 3 * i];
    bt[i] = (const float*)d_in[4 + 3 * i];
  }
  const float* P0 = (const float*)d_in[23];
  const float* P1 = (const float*)d_in[24];
  const float* P2 = (const float*)d_in[25];
  const float* P3 = (const float*)d_in[26];
  const float* pg0 = (const float*)d_in[27]; const float* pb0 = (const float*)d_in[28];
  const float* pg1 = (const float*)d_in[29]; const float* pb1 = (const float*)d_in[30];
  const float* pg2 = (const float*)d_in[31]; const float* pb2 = (const float*)d_in[32];
  float* out = (float*)d_out;

  float* w = (float*)d_ws;
  float* xx = w;                       // 20000
  int* idx = (int*)(w + 20000);        // 200000 ints
  float* yn = w + 220000;              // 1,280,000
  float* yc = yn + 1280000;            // 1,280,000
  float* wmod = yc + 1280000;          // 8192
  float* zA = wmod + 8192;             // 12,800,000
  float* zB = zA + 12800000;           // 12,800,000
  float* xc = zB + 12800000;           // 3,840,000
  float* z5 = xc + 3840000;            // 20,480,000
  float* glob = z5 + 20480000;         // 2176
  float* bias0 = glob + 2176;          // 512
  float* psum = bias0 + 512;           // 65536
  float* psq = psum + 65536;           // 65536
  float* scale = psq + 65536;          // 1024
  float* shift = scale + 1024;         // 1024
  float* hA = zA;                      // head aliases (after knn use)
  float* hB = zB;
  unsigned long long* pk = (unsigned long long*)zA;  // knn scratch, 12.8 MB

  const long xcbs = (long)192 * N;
  const int qblocks = (N + 255) / 256;
  const int qtiles = (N + 63) / 64;

  auto gemm = [&](const float* W, int Wld, const float* X, long xbs, float* Y,
                  const float* bias, int Co, int Cin, int M) {
    dim3 g((M + 127) / 128, (Co + 63) / 64, B);
    gemm_t_kernel<0><<<g, 256, 0, stream>>>(W, Wld, X, xbs, nullptr, nullptr,
                                            nullptr, nullptr, Y, bias, Co, Cin, M);
  };
  auto gemm_n = [&](const float* W, int Wld, const float* X, long xbs, float* Y,
                    int Co, int Cin, int M) {
    dim3 g((M + 127) / 128, (Co + 63) / 64, B);
    gemm_t_kernel<1><<<g, 256, 0, stream>>>(W, Wld, X, xbs, nullptr, nullptr,
                                            scale, shift, Y, nullptr, Co, Cin, M);
  };
  auto gemm_gn = [&](const float* W, int Wld, float* Y) {
    dim3 g((NK + 127) / 128, 1, B);
    gemm_t_kernel<2><<<g, 256, 0, stream>>>(W, Wld, yn, 0, yc, idx,
                                            scale, shift, Y, nullptr, 64, 64, NK);
  };
  auto finalize = [&](const float* g, const float* bb, int C, float inv_n) {
    finalize_kernel<<<(C + 255) / 256, 256, 0, stream>>>(psum, psq, g, bb, scale,
                                                         shift, C, inv_n);
  };
  auto stats = [&](const float* Z, int C, int M) {
    stats_kernel<<<dim3(C, SB), 256, 0, stream>>>(Z, C, M, psum, psq);
  };
  auto knn3 = [&](const float* X, long bstride) {
    xx_kernel<<<dim3(qblocks, B), 256, 0, stream>>>(X, bstride, 3, xx);
    knn_partial_kernel<3, 256, 4><<<dim3(qblocks, JS, B), 256, 0, stream>>>(X, bstride, xx, pk);
    knn_merge_kernel<<<(B * N + 255) / 256, 256, 0, stream>>>(pk, idx);
  };
  auto knn64 = [&](const float* X, long bstride) {
    xx_kernel<<<dim3(qblocks, B), 256, 0, stream>>>(X, bstride, 64, xx);
    knn64_tiled_kernel<<<dim3(qtiles, JS, B), 256, 0, stream>>>(X, bstride, xx, pk);
    knn_merge_kernel<<<(B * N + 255) / 256, 256, 0, stream>>>(pk, idx);
  };
  auto edge_pre = [&](const float* Wconv, int Wld, int Cin, const float* X, long xbs,
                      const float* g, const float* bb) {
    gemm(Wconv, Wld, X, xbs, yn, nullptr, 64, Cin, N);
    wdiff_kernel<<<(64 * Cin + 255) / 256, 256, 0, stream>>>(Wconv, Wld, Cin, 64, wmod);
    gemm(wmod, Cin, X, xbs, yc, nullptr, 64, Cin, N);
    stats_g_kernel<<<dim3(64, SB), 256, 0, stream>>>(yn, yc, idx, psum, psq);
    finalize(g, bb, 64, 1.f / (float)(B * NK));
  };
  const int mk_blocks = (int)(((long)B * 64 * N + 255) / 256);

  // ---- Stage 1 ----
  knn3(pts, (long)3 * N);
  edge_pre(Wt7[0], 6, 3, pts, (long)3 * N, gt[0], bt[0]);
  gemm_gn(Wt7[1], 64, zB);
  stats(zB, 64, NK);
  finalize(gt[1], bt[1], 64, 1.f / (float)(B * NK));
  norm_maxk_kernel<<<mk_blocks, 256, 0, stream>>>(zB, scale, shift, xc, 0);

  // ---- Stage 2 ----
  const float* x1 = xc;
  knn64(x1, xcbs);
  edge_pre(Wt7[2], 128, 64, x1, xcbs, gt[2], bt[2]);
  gemm_gn(Wt7[3], 64, zB);
  stats(zB, 64, NK);
  finalize(gt[3], bt[3], 64, 1.f / (float)(B * NK));
  norm_maxk_kernel<<<mk_blocks, 256, 0, stream>>>(zB, scale, shift, xc, 64);

  // ---- Stage 3 (edge tensor never materialized) ----
  const float* x2 = xc + (long)64 * N;
  knn64(x2, xcbs);
  edge_pre(Wt7[4], 128, 64, x2, xcbs, gt[4], bt[4]);
  norm_maxk_g_kernel<<<mk_blocks, 256, 0, stream>>>(yn, yc, idx, scale, shift, xc, 128);

  // ---- Stage 4: global feature ----
  gemm(Wt7[5], 192, xc, xcbs, z5, nullptr, 1024, 192, N);
  stats(z5, 1024, N);
  finalize(gt[5], bt[5], 1024, 1.f / (float)(B * N));
  norm_gmax_kernel<<<B * 1024, 256, 0, stream>>>(z5, scale, shift, glob);
  lfeat_kernel<<<1, 64, 0, stream>>>(label, Wt7[6], gt[6], bt[6], glob);
  bias0_kernel<<<2, 256, 0, stream>>>(P0, glob, bias0);

  // ---- Stage 5: point head (norm fused into consumer staging) ----
  gemm(P0, 1280, xc, xcbs, hA, bias0, 256, 192, N);
  stats(hA, 256, N);
  finalize(pg0, pb0, 256, 1.f / (float)(B * N));
  gemm_n(P1, 256, hA, (long)256 * N, hB, 256, 256, N);
  stats(hB, 256, N);
  finalize(pg1, pb1, 256, 1.f / (float)(B * N));
  gemm_n(P2, 256, hB, (long)256 * N, hA, 128, 256, N);
  stats(hA, 128, N);
  finalize(pg2, pb2, 128, 1.f / (float)(B * N));
  gemm_n(P3, 128, hA, (long)128 * N, out, 6, 128, N);
}

// Round 11
// 2885.678 us; speedup vs baseline: 1.0812x; 1.0812x over previous
//
#include <hip/hip_runtime.h>
#include <math.h>

constexpr int B = 2;
constexpr int N = 10000;
constexpr int K = 10;
constexpr int NK = N * K;
constexpr float NEG = 0.2f;
constexpr float BN_EPS = 1e-5f;
constexpr int SB = 64;   // stats partial blocks per channel
constexpr int JS = 8;    // knn j-range splits
constexpr int JT = 64;   // knn64 j-tile

#define DEV __device__ __forceinline__

// ---------------- squared norms ----------------
__global__ void __launch_bounds__(256, 4)
xx_kernel(const float* __restrict__ x, long bstride, int C,
          float* __restrict__ xx) {
  int n = blockIdx.x * 256 + threadIdx.x;
  int b = blockIdx.y;
  if (n >= N) return;
  const float* xb = x + (long)b * bstride;
  float s = 0.f;
  for (int c = 0; c < C; ++c) { float v = xb[(long)c * N + n]; s += v * v; }
  xx[b * N + n] = s;
}

// ---------------- u64 packed key: (monotone f32 bits)<<32 | j ----------------
DEV unsigned int fkey(float d) {
  unsigned int b = __float_as_uint(d);
  return b ^ (((unsigned int)((int)b >> 31)) | 0x80000000u);
}
DEV unsigned long long pack_key(float d, unsigned int j) {
  return ((unsigned long long)fkey(d) << 32) | j;
}
DEV void topk_u64(unsigned long long (&best)[K], unsigned long long key) {
#pragma unroll
  for (int s = 0; s < K; ++s) {
    unsigned long long b = best[s];
    bool lt = key < b;
    best[s] = lt ? key : b;
    key = lt ? b : key;
  }
}
constexpr unsigned long long KEY_MAX = 0xFFFFFFFFFFFFFFFFull;

// ---------------- knn partial for C=3 (cheap, per-thread query) ----------------
template<int C, int TJ, int PAD>
__global__ void __launch_bounds__(256, 4)
knn_partial_kernel(const float* __restrict__ x, long bstride,
                   const float* __restrict__ xx,
                   unsigned long long* __restrict__ pk) {
  __shared__ __align__(16) float sx[TJ][PAD];
  __shared__ float sxx[TJ];
  int b = blockIdx.z;
  int js = blockIdx.y;
  int q = blockIdx.x * 256 + threadIdx.x;
  bool valid = q < N;
  const int CH = (N + JS - 1) / JS;
  int jbeg = js * CH;
  int jend = min(N, jbeg + CH);
  const float* xb = x + (long)b * bstride;
  float xi[C];
  float xxi = 0.f;
  if (valid) {
#pragma unroll
    for (int c = 0; c < C; ++c) xi[c] = xb[(long)c * N + q];
    xxi = xx[b * N + q];
  }
  unsigned long long best[K];
#pragma unroll
  for (int k = 0; k < K; ++k) best[k] = KEY_MAX;

  for (int j0 = jbeg; j0 < jend; j0 += TJ) {
    int cnt = min(TJ, jend - j0);
    __syncthreads();
    for (int e = threadIdx.x; e < C * TJ; e += 256) {
      int tj = e & (TJ - 1);
      int c = e / TJ;
      sx[tj][c] = (tj < cnt) ? xb[(long)c * N + j0 + tj] : 0.f;
    }
    for (int e = threadIdx.x; e < TJ; e += 256)
      sxx[e] = (e < cnt) ? xx[b * N + j0 + e] : 0.f;
    __syncthreads();
    if (!valid) continue;
    for (int tj = 0; tj < cnt; ++tj) {
      float dot = 0.f;
#pragma unroll
      for (int c = 0; c < C; ++c) dot += xi[c] * sx[tj][c];
      float d = xxi - 2.f * dot + sxx[tj];
      int j = j0 + tj;
      if (j != q) {
        unsigned long long key = pack_key(d, (unsigned int)j);
        if (key < best[K - 1]) topk_u64(best, key);
      }
    }
  }
  if (valid) {
    long base = ((long)(b * N + q) * JS + js) * K;
#pragma unroll
    for (int k = 0; k < K; ++k) pk[base + k] = best[k];
  }
}

// ---------------- knn C=64: tiled distance-GEMM + fused top-k ----------------
// PROVEN ARTIFACT (R4/R8/R9 bench: ~802us, VGPR 64, no spill) — FROZEN.
// R10's JT=128 variant regressed (occupancy 39->30, dur 802->910): reverted.
__global__ void __launch_bounds__(256, 4)
knn64_tiled_kernel(const float* __restrict__ x, long bstride,
                   const float* __restrict__ xx,
                   unsigned long long* __restrict__ pk) {
  __shared__ __align__(16) float smem[64 * 68 * 2 + 128];
  float* Qt = smem;                 // [c][q] pad 68
  float* JD = smem + 64 * 68;      // [c][j] pad 68; reused as D[j][q] pad 68
  float* xxq = smem + 64 * 68 * 2;
  float* xxj = xxq + 64;
  int b = blockIdx.z, js = blockIdx.y, qt = blockIdx.x;
  int t = threadIdx.x;
  const float* xb = x + (long)b * bstride;
  const float* xxb = xx + b * N;
  int q0 = qt * 64;
#pragma unroll
  for (int r = 0; r < 16; ++r) {
    int e = t + r * 256;
    int q = e & 63, c = e >> 6;
    int qg = q0 + q;
    Qt[c * 68 + q] = (qg < N) ? xb[(long)c * N + qg] : 0.f;
  }
  if (t < 64) xxq[t] = (q0 + t < N) ? xxb[q0 + t] : 0.f;

  const int CH = N / JS;               // 1250
  int jbeg = js * CH, jend = jbeg + CH;
  int tx = t & 15, ty = t >> 4;
  int sq = t & 63, quarter = t >> 6;

  unsigned long long best[K];
#pragma unroll
  for (int k = 0; k < K; ++k) best[k] = KEY_MAX;

  for (int jb = jbeg; jb < jend; jb += JT) {
    __syncthreads();
#pragma unroll
    for (int r = 0; r < 16; ++r) {
      int e = t + r * 256;
      int j = e & 63, c = e >> 6;
      int jg = jb + j;
      JD[c * 68 + j] = (jg < jend) ? xb[(long)c * N + jg] : 0.f;
    }
    if (t < 64) xxj[t] = (jb + t < jend) ? xxb[jb + t] : 3.4e38f;
    __syncthreads();

    float acc[4][4] = {};
#pragma unroll 4
    for (int c = 0; c < 64; ++c) {
      float4 aq = *(const float4*)&Qt[c * 68 + tx * 4];
      float4 bj = *(const float4*)&JD[c * 68 + ty * 4];
      float av[4] = {aq.x, aq.y, aq.z, aq.w};
      float bv[4] = {bj.x, bj.y, bj.z, bj.w};
#pragma unroll
      for (int i = 0; i < 4; ++i)
#pragma unroll
        for (int jj = 0; jj < 4; ++jj) acc[i][jj] += av[i] * bv[jj];
    }
    __syncthreads();

    float4 xxjv = *(const float4*)&xxj[ty * 4];
    float xjv[4] = {xxjv.x, xxjv.y, xxjv.z, xxjv.w};
    int selbase = q0 + tx * 4 - jb - ty * 4;
    float d4[4][4];
#pragma unroll
    for (int i = 0; i < 4; ++i) {
      float xq = xxq[tx * 4 + i];
#pragma unroll
      for (int jj = 0; jj < 4; ++jj) {
        float dv = xq - 2.f * acc[i][jj] + xjv[jj];
        d4[i][jj] = (selbase + i == jj) ? 3.4e38f : dv;
      }
    }
#pragma unroll
    for (int jj = 0; jj < 4; ++jj) {
      float4 sv = make_float4(d4[0][jj], d4[1][jj], d4[2][jj], d4[3][jj]);
      *(float4*)&JD[(ty * 4 + jj) * 68 + tx * 4] = sv;
    }
    __syncthreads();

#pragma unroll 4
    for (int jj = 0; jj < 16; ++jj) {
      int jl = quarter * 16 + jj;
      float dv = JD[jl * 68 + sq];
      unsigned long long key = pack_key(dv, (unsigned int)(jb + jl));
      if (key < best[K - 1]) topk_u64(best, key);
    }
  }
  __syncthreads();
  unsigned long long* mb = (unsigned long long*)smem;
#pragma unroll
  for (int k = 0; k < K; ++k) mb[(sq * 4 + quarter) * K + k] = best[k];
  __syncthreads();
  if (t < 64 && q0 + t < N) {
    unsigned long long fb[K];
#pragma unroll
    for (int k = 0; k < K; ++k) fb[k] = KEY_MAX;
    for (int s = 0; s < 4; ++s)
#pragma unroll
      for (int k = 0; k < K; ++k) {
        unsigned long long key = mb[(t * 4 + s) * K + k];
        if (key < fb[K - 1]) topk_u64(fb, key);
      }
    long base = ((long)(b * N + q0 + t) * JS + js) * K;
#pragma unroll
    for (int k = 0; k < K; ++k) pk[base + k] = fb[k];
  }
}

// ---------------- knn merge ----------------
__global__ void __launch_bounds__(256, 4)
knn_merge_kernel(const unsigned long long* __restrict__ pk, int* __restrict__ idx) {
  int t = blockIdx.x * 256 + threadIdx.x;
  if (t >= B * N) return;
  unsigned long long best[K];
#pragma unroll
  for (int k = 0; k < K; ++k) best[k] = KEY_MAX;
  for (int s = 0; s < JS; ++s) {
    long base = ((long)t * JS + s) * K;
#pragma unroll
    for (int k = 0; k < K; ++k) {
      unsigned long long key = pk[base + k];
      if (key < best[K - 1]) topk_u64(best, key);
    }
  }
#pragma unroll
  for (int k = 0; k < K; ++k)
    idx[(long)t * K + k] = (int)(best[k] & 0xFFFFFFFFull);
}

// ---------------- templated tiled SGEMM ----------------
// MODE 0: plain X.  MODE 1: X staged through lrelu(x*scale[c]+shift[c]).
// MODE 2: X = lrelu(scale[c]*(ync[b][c][idx[m]] + ync[b][64+c][m/K]) + shift[c])
//         (gather+norm; ync is the combined [b][128][N] edge buffer).
template<int MODE>
__global__ void __launch_bounds__(256, 2)
gemm_t_kernel(const float* __restrict__ W, int Wld,
              const float* __restrict__ X, long xbstride,
              const int* __restrict__ idx,
              const float* __restrict__ scale, const float* __restrict__ shift,
              float* __restrict__ Y, const float* __restrict__ bias,
              int Co, int Cin, int M) {
  __shared__ __align__(16) float Wt[16][64];
  __shared__ __align__(16) float Xt[16][128];
  __shared__ int jn_s[128];
  __shared__ int nn_s[128];
  int b = blockIdx.z;
  int m0 = blockIdx.x * 128;
  int o0 = blockIdx.y * 64;
  int t = threadIdx.x;
  int tx = t & 15, ty = t >> 4;
  if constexpr (MODE == 2) {
    if (t < 128) {
      int m = m0 + t;
      int n = 0, j = 0;
      if (m < M) { n = m / K; j = idx[(long)b * N * K + m]; }
      nn_s[t] = n; jn_s[t] = j;
    }
    __syncthreads();
  }
  float acc[4][8] = {};
  for (int c0 = 0; c0 < Cin; c0 += 16) {
#pragma unroll
    for (int r = 0; r < 4; ++r) {
      int e = t + r * 256;
      int o = e & 63, kc = e >> 6;
      int oo = o0 + o, cc = c0 + kc;
      Wt[kc][o] = (oo < Co && cc < Cin) ? W[(long)oo * Wld + cc] : 0.f;
    }
    {
      int kc = t >> 4, ms = (t & 15) * 8;
      int cc = c0 + kc;
      int mm = m0 + ms;
      float xv[8];
      if constexpr (MODE == 2) {
        const float* ynr = X + ((long)b * 128 + cc) * N;
        const float* ycr = X + ((long)b * 128 + 64 + cc) * N;
        float sc = scale[cc], sh = shift[cc];
#pragma unroll
        for (int r = 0; r < 8; ++r) {
          int m = mm + r;
          float v = 0.f;
          if (m < M) {
            v = ynr[jn_s[ms + r]] + ycr[nn_s[ms + r]];
            v = v * sc + sh;
            v = v >= 0.f ? v : NEG * v;
          }
          xv[r] = v;
        }
      } else {
        bool okc = cc < Cin;
        const float* Xr = X + (long)b * xbstride + (long)cc * M;
        if (okc && mm + 8 <= M) {
          float4 a0 = *(const float4*)&Xr[mm];
          float4 a1 = *(const float4*)&Xr[mm + 4];
          xv[0] = a0.x; xv[1] = a0.y; xv[2] = a0.z; xv[3] = a0.w;
          xv[4] = a1.x; xv[5] = a1.y; xv[6] = a1.z; xv[7] = a1.w;
        } else {
#pragma unroll
          for (int r = 0; r < 8; ++r)
            xv[r] = (okc && mm + r < M) ? Xr[mm + r] : 0.f;
        }
        if constexpr (MODE == 1) {
          float sc = okc ? scale[cc] : 0.f;
          float sh = okc ? shift[cc] : 0.f;
#pragma unroll
          for (int r = 0; r < 8; ++r) {
            float v = xv[r] * sc + sh;
            xv[r] = v >= 0.f ? v : NEG * v;
          }
        }
      }
      *(float4*)&Xt[kc][ms] = make_float4(xv[0], xv[1], xv[2], xv[3]);
      *(float4*)&Xt[kc][ms + 4] = make_float4(xv[4], xv[5], xv[6], xv[7]);
    }
    __syncthreads();
#pragma unroll
    for (int kc = 0; kc < 16; ++kc) {
      float4 a = *(const float4*)&Wt[kc][ty * 4];
      float4 x0 = *(const float4*)&Xt[kc][tx * 4];
      float4 x1 = *(const float4*)&Xt[kc][64 + tx * 4];
      float av[4] = {a.x, a.y, a.z, a.w};
      float xr[8] = {x0.x, x0.y, x0.z, x0.w, x1.x, x1.y, x1.z, x1.w};
#pragma unroll
      for (int i = 0; i < 4; ++i)
#pragma unroll
        for (int j = 0; j < 8; ++j) acc[i][j] += av[i] * xr[j];
    }
    __syncthreads();
  }
#pragma unroll
  for (int i = 0; i < 4; ++i) {
    int oo = o0 + ty * 4 + i;
    if (oo >= Co) continue;
    float bv = bias ? bias[b * Co + oo] : 0.f;
    long ybase = ((long)b * Co + oo) * M;
    int mlo = m0 + tx * 4, mhi = m0 + 64 + tx * 4;
    if (mlo + 4 <= M) {
      float4 v = make_float4(acc[i][0] + bv, acc[i][1] + bv,
                             acc[i][2] + bv, acc[i][3] + bv);
      *(float4*)&Y[ybase + mlo] = v;
    } else {
#pragma unroll
      for (int j = 0; j < 4; ++j)
        if (mlo + j < M) Y[ybase + mlo + j] = acc[i][j] + bv;
    }
    if (mhi + 4 <= M) {
      float4 v = make_float4(acc[i][4] + bv, acc[i][5] + bv,
                             acc[i][6] + bv, acc[i][7] + bv);
      *(float4*)&Y[ybase + mhi] = v;
    } else {
#pragma unroll
      for (int j = 0; j < 4; ++j)
        if (mhi + j < M) Y[ybase + mhi + j] = acc[i][j + 4] + bv;
    }
  }
}

// ---------------- wcomb[o][c]: rows 0..63 = W_L, rows 64..127 = W_R - W_L ----------------
__global__ void wcomb_kernel(const float* __restrict__ W, int Wld, int Cin,
                             float* __restrict__ wcomb) {
  int e = blockIdx.x * 256 + threadIdx.x;
  if (e < 128 * Cin) {
    int o = e / Cin, c = e % Cin;
    wcomb[e] = (o < 64) ? W[o * Wld + c]
                        : (W[(o - 64) * Wld + Cin + c] - W[(o - 64) * Wld + c]);
  }
}

// ---------------- stats over materialized tensor ----------------
__global__ void __launch_bounds__(256, 4)
stats_kernel(const float* __restrict__ X, int C, int M,
             float* __restrict__ psum, float* __restrict__ psq) {
  int c = blockIdx.x, s = blockIdx.y;
  float sum = 0.f, sq = 0.f;
  for (int b = 0; b < B; ++b) {
    const float* p = X + ((long)b * C + c) * M;
    for (int m = s * 256 + threadIdx.x; m < M; m += SB * 256) {
      float v = p[m];
      sum += v; sq += v * v;
    }
  }
#pragma unroll
  for (int off = 32; off; off >>= 1) {
    sum += __shfl_down(sum, off);
    sq += __shfl_down(sq, off);
  }
  __shared__ float ls[8];
  int wid = threadIdx.x >> 6;
  if ((threadIdx.x & 63) == 0) { ls[wid] = sum; ls[4 + wid] = sq; }
  __syncthreads();
  if (threadIdx.x == 0) {
    psum[c * SB + s] = ls[0] + ls[1] + ls[2] + ls[3];
    psq[c * SB + s] = ls[4] + ls[5] + ls[6] + ls[7];
  }
}

// ---------------- stats over gathered edge tensor (combined ync buffer) ----------------
__global__ void __launch_bounds__(256, 4)
stats_g_kernel(const float* __restrict__ ync, const int* __restrict__ idx,
               float* __restrict__ psum, float* __restrict__ psq) {
  int c = blockIdx.x, s = blockIdx.y;
  float sum = 0.f, sq = 0.f;
  for (int b = 0; b < B; ++b) {
    const float* ynr = ync + ((long)b * 128 + c) * N;
    const float* ycr = ync + ((long)b * 128 + 64 + c) * N;
    const int* ib = idx + (long)b * N * K;
    for (int m = s * 256 + threadIdx.x; m < NK; m += SB * 256) {
      int n = m / K;
      float v = ynr[ib[m]] + ycr[n];
      sum += v; sq += v * v;
    }
  }
#pragma unroll
  for (int off = 32; off; off >>= 1) {
    sum += __shfl_down(sum, off);
    sq += __shfl_down(sq, off);
  }
  __shared__ float ls[8];
  int wid = threadIdx.x >> 6;
  if ((threadIdx.x & 63) == 0) { ls[wid] = sum; ls[4 + wid] = sq; }
  __syncthreads();
  if (threadIdx.x == 0) {
    psum[c * SB + s] = ls[0] + ls[1] + ls[2] + ls[3];
    psq[c * SB + s] = ls[4] + ls[5] + ls[6] + ls[7];
  }
}

__global__ void finalize_kernel(const float* __restrict__ psum, const float* __restrict__ psq,
                                const float* __restrict__ g, const float* __restrict__ bb,
                                float* __restrict__ scale, float* __restrict__ shift,
                                int C, float inv_n) {
  int c = blockIdx.x * 256 + threadIdx.x;
  if (c >= C) return;
  float s = 0.f, q = 0.f;
  for (int i = 0; i < SB; ++i) { s += psum[c * SB + i]; q += psq[c * SB + i]; }
  float mean = s * inv_n;
  float var = q * inv_n - mean * mean;
  float sc = g[c] * rsqrtf(var + BN_EPS);
  scale[c] = sc;
  shift[c] = bb[c] - mean * sc;
}

// ---------------- fused norm+lrelu+max-over-K (materialized Z) ----------------
__global__ void __launch_bounds__(256, 4)
norm_maxk_kernel(const float* __restrict__ Z, const float* __restrict__ scale,
                 const float* __restrict__ shift, float* __restrict__ xc, int coff) {
  long e = (long)blockIdx.x * 256 + threadIdx.x;
  if (e >= (long)B * 64 * N) return;
  int n = (int)(e % N);
  long t = e / N;
  int o = (int)(t % 64);
  int b = (int)(t / 64);
  const float* p = Z + (((long)(b * 64 + o) * N) + n) * K;
  float sc = scale[o], sh = shift[o];
  float m = -3.4e38f;
#pragma unroll
  for (int k = 0; k < K; ++k) {
    float v = p[k] * sc + sh;
    v = v >= 0.f ? v : NEG * v;
    m = fmaxf(m, v);
  }
  xc[((long)b * 192 + coff + o) * N + n] = m;
}

// ---------------- fused gather+norm+lrelu+max-over-K (combined ync) ----------------
__global__ void __launch_bounds__(256, 4)
norm_maxk_g_kernel(const float* __restrict__ ync, const int* __restrict__ idx,
                   const float* __restrict__ scale, const float* __restrict__ shift,
                   float* __restrict__ xc, int coff) {
  long e = (long)blockIdx.x * 256 + threadIdx.x;
  if (e >= (long)B * 64 * N) return;
  int n = (int)(e % N);
  long t = e / N;
  int o = (int)(t % 64);
  int b = (int)(t / 64);
  const int* ib = idx + ((long)b * N + n) * K;
  const float* ynr = ync + ((long)b * 128 + o) * N;
  float ycv = ync[((long)b * 128 + 64 + o) * N + n];
  float sc = scale[o], sh = shift[o];
  float m = -3.4e38f;
#pragma unroll
  for (int k = 0; k < K; ++k) {
    float v = (ynr[ib[k]] + ycv) * sc + sh;
    v = v >= 0.f ? v : NEG * v;
    m = fmaxf(m, v);
  }
  xc[((long)b * 192 + coff + o) * N + n] = m;
}

// ---------------- fused norm+lrelu+max over N (z5 -> glob[0:1024]) ----------------
__global__ void __launch_bounds__(256, 4)
norm_gmax_kernel(const float* __restrict__ Z5, const float* __restrict__ scale,
                 const float* __restrict__ shift, float* __restrict__ glob) {
  int r = blockIdx.x;  // B*1024
  int b = r >> 10, o = r & 1023;
  const float* p = Z5 + (long)r * N;
  float sc = scale[o], sh = shift[o];
  float m = -3.4e38f;
  for (int n = threadIdx.x; n < N; n += 256) {
    float v = p[n] * sc + sh;
    v = v >= 0.f ? v : NEG * v;
    m = fmaxf(m, v);
  }
#pragma unroll
  for (int off = 32; off; off >>= 1) m = fmaxf(m, __shfl_down(m, off));
  __shared__ float ls[4];
  int wid = threadIdx.x >> 6;
  if ((threadIdx.x & 63) == 0) ls[wid] = m;
  __syncthreads();
  if (threadIdx.x == 0)
    glob[b * 1088 + o] = fmaxf(fmaxf(ls[0], ls[1]), fmaxf(ls[2], ls[3]));
}

// ---------------- label branch (tiny) ----------------
__global__ void lfeat_kernel(const float* __restrict__ label, const float* __restrict__ W6,
                             const float* __restrict__ g6, const float* __restrict__ b6,
                             float* __restrict__ glob) {
  int o = threadIdx.x;
  if (o >= 64) return;
  float v[B];
  for (int b = 0; b < B; ++b) {
    float s = 0.f;
    for (int c = 0; c < 16; ++c) s += W6[o * 16 + c] * label[b * 16 + c];
    v[b] = s;
  }
  float mean = 0.f;
  for (int b = 0; b < B; ++b) mean += v[b];
  mean *= (1.f / B);
  float var = 0.f;
  for (int b = 0; b < B; ++b) var += (v[b] - mean) * (v[b] - mean);
  var *= (1.f / B);
  float sc = g6[o] * rsqrtf(var + BN_EPS);
  for (int b = 0; b < B; ++b) {
    float t = (v[b] - mean) * sc + b6[o];
    glob[b * 1088 + 1024 + o] = t >= 0.f ? t : NEG * t;
  }
}

// ---------------- bias0[b][o] = sum_c P0[o][192+c] * glob[b][c] ----------------
__global__ void __launch_bounds__(256, 4)
bias0_kernel(const float* __restrict__ P0, const float* __restrict__ glob,
             float* __restrict__ bias0) {
  int t = blockIdx.x * 256 + threadIdx.x;
  if (t >= B * 256) return;
  int b = t >> 8, o = t & 255;
  float s = 0.f;
  for (int c = 0; c < 1088; ++c) s += P0[o * 1280 + 192 + c] * glob[b * 1088 + c];
  bias0[b * 256 + o] = s;
}

extern "C" void kernel_launch(void* const* d_in, const int* in_sizes, int n_in,
                              void* d_out, int out_size, void* d_ws, size_t ws_size,
                              hipStream_t stream) {
  const float* pts = (const float*)d_in[0];
  const float* label = (const float*)d_in[1];
  const float* Wt7[7]; const float* gt[7]; const float* bt[7];
  for (int i = 0; i < 7; ++i) {
    Wt7[i] = (const float*)d_in[2 + 3 * i];
    gt[i] = (const float*)d_in[3 + 3 * i];
    bt[i] = (const float*)d_in[4 + 3 * i];
  }
  const float* P0 = (const float*)d_in[23];
  const float* P1 = (const float*)d_in[24];
  const float* P2 = (const float*)d_in[25];
  const float* P3 = (const float*)d_in[26];
  const float* pg0 = (const float*)d_in[27]; const float* pb0 = (const float*)d_in[28];
  const float* pg1 = (const float*)d_in[29]; const float* pb1 = (const float*)d_in[30];
  const float* pg2 = (const float*)d_in[31]; const float* pb2 = (const float*)d_in[32];
  float* out = (float*)d_out;

  float* w = (float*)d_ws;
  float* xx = w;                       // 20000
  int* idx = (int*)(w + 20000);        // 200000 ints
  float* ync = w + 220000;             // combined edge buffer [B][128][N] = 2,560,000
  float* wcomb = ync + 2560000;        // 8192
  float* zA = wcomb + 8192;            // 12,800,000
  float* zB = zA + 12800000;           // 12,800,000
  float* xc = zB + 12800000;           // 3,840,000
  float* z5 = xc + 3840000;            // 20,480,000
  float* glob = z5 + 20480000;         // 2176
  float* bias0 = glob + 2176;          // 512
  float* psum = bias0 + 512;           // 65536
  float* psq = psum + 65536;           // 65536
  float* scale = psq + 65536;          // 1024
  float* shift = scale + 1024;         // 1024
  float* hA = zA;                      // head aliases (after knn use)
  float* hB = zB;
  unsigned long long* pk = (unsigned long long*)zA;  // knn scratch, 12.8 MB

  const long xcbs = (long)192 * N;
  const int qblocks = (N + 255) / 256;
  const int qtiles = (N + 63) / 64;

  auto gemm = [&](const float* W, int Wld, const float* X, long xbs, float* Y,
                  const float* bias, int Co, int Cin, int M) {
    dim3 g((M + 127) / 128, (Co + 63) / 64, B);
    gemm_t_kernel<0><<<g, 256, 0, stream>>>(W, Wld, X, xbs, nullptr,
                                            nullptr, nullptr, Y, bias, Co, Cin, M);
  };
  auto gemm_n = [&](const float* W, int Wld, const float* X, long xbs, float* Y,
                    int Co, int Cin, int M) {
    dim3 g((M + 127) / 128, (Co + 63) / 64, B);
    gemm_t_kernel<1><<<g, 256, 0, stream>>>(W, Wld, X, xbs, nullptr,
                                            scale, shift, Y, nullptr, Co, Cin, M);
  };
  auto gemm_gn = [&](const float* W, int Wld, float* Y) {
    dim3 g((NK + 127) / 128, 1, B);
    gemm_t_kernel<2><<<g, 256, 0, stream>>>(W, Wld, ync, 0, idx,
                                            scale, shift, Y, nullptr, 64, 64, NK);
  };
  auto finalize = [&](const float* g, const float* bb, int C, float inv_n) {
    finalize_kernel<<<(C + 255) / 256, 256, 0, stream>>>(psum, psq, g, bb, scale,
                                                         shift, C, inv_n);
  };
  auto stats = [&](const float* Z, int C, int M) {
    stats_kernel<<<dim3(C, SB), 256, 0, stream>>>(Z, C, M, psum, psq);
  };
  auto knn3 = [&](const float* X, long bstride) {
    xx_kernel<<<dim3(qblocks, B), 256, 0, stream>>>(X, bstride, 3, xx);
    knn_partial_kernel<3, 256, 4><<<dim3(qblocks, JS, B), 256, 0, stream>>>(X, bstride, xx, pk);
    knn_merge_kernel<<<(B * N + 255) / 256, 256, 0, stream>>>(pk, idx);
  };
  auto knn64 = [&](const float* X, long bstride) {
    xx_kernel<<<dim3(qblocks, B), 256, 0, stream>>>(X, bstride, 64, xx);
    knn64_tiled_kernel<<<dim3(qtiles, JS, B), 256, 0, stream>>>(X, bstride, xx, pk);
    knn_merge_kernel<<<(B * N + 255) / 256, 256, 0, stream>>>(pk, idx);
  };
  auto edge_pre = [&](const float* Wconv, int Wld, int Cin, const float* X, long xbs,
                      const float* g, const float* bb) {
    // ync[b][0:64] = W_L @ x ; ync[b][64:128] = (W_R - W_L) @ x  (one Co=128 gemm)
    wcomb_kernel<<<(128 * Cin + 255) / 256, 256, 0, stream>>>(Wconv, Wld, Cin, wcomb);
    gemm(wcomb, Cin, X, xbs, ync, nullptr, 128, Cin, N);
    stats_g_kernel<<<dim3(64, SB), 256, 0, stream>>>(ync, idx, psum, psq);
    finalize(g, bb, 64, 1.f / (float)(B * NK));
  };
  const int mk_blocks = (int)(((long)B * 64 * N + 255) / 256);

  // ---- Stage 1 ----
  knn3(pts, (long)3 * N);
  edge_pre(Wt7[0], 6, 3, pts, (long)3 * N, gt[0], bt[0]);
  gemm_gn(Wt7[1], 64, zB);
  stats(zB, 64, NK);
  finalize(gt[1], bt[1], 64, 1.f / (float)(B * NK));
  norm_maxk_kernel<<<mk_blocks, 256, 0, stream>>>(zB, scale, shift, xc, 0);

  // ---- Stage 2 ----
  const float* x1 = xc;
  knn64(x1, xcbs);
  edge_pre(Wt7[2], 128, 64, x1, xcbs, gt[2], bt[2]);
  gemm_gn(Wt7[3], 64, zB);
  stats(zB, 64, NK);
  finalize(gt[3], bt[3], 64, 1.f / (float)(B * NK));
  norm_maxk_kernel<<<mk_blocks, 256, 0, stream>>>(zB, scale, shift, xc, 64);

  // ---- Stage 3 (edge tensor never materialized) ----
  const float* x2 = xc + (long)64 * N;
  knn64(x2, xcbs);
  edge_pre(Wt7[4], 128, 64, x2, xcbs, gt[4], bt[4]);
  norm_maxk_g_kernel<<<mk_blocks, 256, 0, stream>>>(ync, idx, scale, shift, xc, 128);

  // ---- Stage 4: global feature ----
  gemm(Wt7[5], 192, xc, xcbs, z5, nullptr, 1024, 192, N);
  stats(z5, 1024, N);
  finalize(gt[5], bt[5], 1024, 1.f / (float)(B * N));
  norm_gmax_kernel<<<B * 1024, 256, 0, stream>>>(z5, scale, shift, glob);
  lfeat_kernel<<<1, 64, 0, stream>>>(label, Wt7[6], gt[6], bt[6], glob);
  bias0_kernel<<<2, 256, 0, stream>>>(P0, glob, bias0);

  // ---- Stage 5: point head (norm fused into consumer staging) ----
  gemm(P0, 1280, xc, xcbs, hA, bias0, 256, 192, N);
  stats(hA, 256, N);
  finalize(pg0, pb0, 256, 1.f / (float)(B * N));
  gemm_n(P1, 256, hA, (long)256 * N, hB, 256, 256, N);
  stats(hB, 256, N);
  finalize(pg1, pb1, 256, 1.f / (float)(B * N));
  gemm_n(P2, 256, hB, (long)256 * N, hA, 128, 256, N);
  stats(hA, 128, N);
  finalize(pg2, pb2, 128, 1.f / (float)(B * N));
  gemm_n(P3, 128, hA, (long)128 * N, out, 6, 128, N);
}

// Round 12
// 2877.101 us; speedup vs baseline: 1.0844x; 1.0030x over previous
//
#include <hip/hip_runtime.h>
#include <math.h>

constexpr int B = 2;
constexpr int N = 10000;
constexpr int K = 10;
constexpr int NK = N * K;
constexpr float NEG = 0.2f;
constexpr float BN_EPS = 1e-5f;
constexpr int SB = 64;   // stats partial blocks per channel
constexpr int JS = 8;    // knn j-range splits
constexpr int JT = 64;   // knn64 j-tile

#define DEV __device__ __forceinline__

// ---------------- squared norms ----------------
__global__ void __launch_bounds__(256, 4)
xx_kernel(const float* __restrict__ x, long bstride, int C,
          float* __restrict__ xx) {
  int n = blockIdx.x * 256 + threadIdx.x;
  int b = blockIdx.y;
  if (n >= N) return;
  const float* xb = x + (long)b * bstride;
  float s = 0.f;
  for (int c = 0; c < C; ++c) { float v = xb[(long)c * N + n]; s += v * v; }
  xx[b * N + n] = s;
}

// ---------------- u64 packed key: (monotone f32 bits)<<32 | j ----------------
DEV unsigned int fkey(float d) {
  unsigned int b = __float_as_uint(d);
  return b ^ (((unsigned int)((int)b >> 31)) | 0x80000000u);
}
DEV unsigned long long pack_key(float d, unsigned int j) {
  return ((unsigned long long)fkey(d) << 32) | j;
}
DEV void topk_u64(unsigned long long (&best)[K], unsigned long long key) {
#pragma unroll
  for (int s = 0; s < K; ++s) {
    unsigned long long b = best[s];
    bool lt = key < b;
    best[s] = lt ? key : b;
    key = lt ? b : key;
  }
}
constexpr unsigned long long KEY_MAX = 0xFFFFFFFFFFFFFFFFull;

// ---------------- knn partial for C=3 (cheap, per-thread query) ----------------
template<int C, int TJ, int PAD>
__global__ void __launch_bounds__(256, 4)
knn_partial_kernel(const float* __restrict__ x, long bstride,
                   const float* __restrict__ xx,
                   unsigned long long* __restrict__ pk) {
  __shared__ __align__(16) float sx[TJ][PAD];
  __shared__ float sxx[TJ];
  int b = blockIdx.z;
  int js = blockIdx.y;
  int q = blockIdx.x * 256 + threadIdx.x;
  bool valid = q < N;
  const int CH = (N + JS - 1) / JS;
  int jbeg = js * CH;
  int jend = min(N, jbeg + CH);
  const float* xb = x + (long)b * bstride;
  float xi[C];
  float xxi = 0.f;
  if (valid) {
#pragma unroll
    for (int c = 0; c < C; ++c) xi[c] = xb[(long)c * N + q];
    xxi = xx[b * N + q];
  }
  unsigned long long best[K];
#pragma unroll
  for (int k = 0; k < K; ++k) best[k] = KEY_MAX;

  for (int j0 = jbeg; j0 < jend; j0 += TJ) {
    int cnt = min(TJ, jend - j0);
    __syncthreads();
    for (int e = threadIdx.x; e < C * TJ; e += 256) {
      int tj = e & (TJ - 1);
      int c = e / TJ;
      sx[tj][c] = (tj < cnt) ? xb[(long)c * N + j0 + tj] : 0.f;
    }
    for (int e = threadIdx.x; e < TJ; e += 256)
      sxx[e] = (e < cnt) ? xx[b * N + j0 + e] : 0.f;
    __syncthreads();
    if (!valid) continue;
    for (int tj = 0; tj < cnt; ++tj) {
      float dot = 0.f;
#pragma unroll
      for (int c = 0; c < C; ++c) dot += xi[c] * sx[tj][c];
      float d = xxi - 2.f * dot + sxx[tj];
      int j = j0 + tj;
      if (j != q) {
        unsigned long long key = pack_key(d, (unsigned int)j);
        if (key < best[K - 1]) topk_u64(best, key);
      }
    }
  }
  if (valid) {
    long base = ((long)(b * N + q) * JS + js) * K;
#pragma unroll
    for (int k = 0; k < K; ++k) pk[base + k] = best[k];
  }
}

// ---------------- knn C=64: tiled distance-GEMM + fused top-k ----------------
// PROVEN ARTIFACT (R4/R8/R9/R11 bench: ~806us, VGPR 64, no spill) — FROZEN.
__global__ void __launch_bounds__(256, 4)
knn64_tiled_kernel(const float* __restrict__ x, long bstride,
                   const float* __restrict__ xx,
                   unsigned long long* __restrict__ pk) {
  __shared__ __align__(16) float smem[64 * 68 * 2 + 128];
  float* Qt = smem;                 // [c][q] pad 68
  float* JD = smem + 64 * 68;      // [c][j] pad 68; reused as D[j][q] pad 68
  float* xxq = smem + 64 * 68 * 2;
  float* xxj = xxq + 64;
  int b = blockIdx.z, js = blockIdx.y, qt = blockIdx.x;
  int t = threadIdx.x;
  const float* xb = x + (long)b * bstride;
  const float* xxb = xx + b * N;
  int q0 = qt * 64;
#pragma unroll
  for (int r = 0; r < 16; ++r) {
    int e = t + r * 256;
    int q = e & 63, c = e >> 6;
    int qg = q0 + q;
    Qt[c * 68 + q] = (qg < N) ? xb[(long)c * N + qg] : 0.f;
  }
  if (t < 64) xxq[t] = (q0 + t < N) ? xxb[q0 + t] : 0.f;

  const int CH = N / JS;               // 1250
  int jbeg = js * CH, jend = jbeg + CH;
  int tx = t & 15, ty = t >> 4;
  int sq = t & 63, quarter = t >> 6;

  unsigned long long best[K];
#pragma unroll
  for (int k = 0; k < K; ++k) best[k] = KEY_MAX;

  for (int jb = jbeg; jb < jend; jb += JT) {
    __syncthreads();
#pragma unroll
    for (int r = 0; r < 16; ++r) {
      int e = t + r * 256;
      int j = e & 63, c = e >> 6;
      int jg = jb + j;
      JD[c * 68 + j] = (jg < jend) ? xb[(long)c * N + jg] : 0.f;
    }
    if (t < 64) xxj[t] = (jb + t < jend) ? xxb[jb + t] : 3.4e38f;
    __syncthreads();

    float acc[4][4] = {};
#pragma unroll 4
    for (int c = 0; c < 64; ++c) {
      float4 aq = *(const float4*)&Qt[c * 68 + tx * 4];
      float4 bj = *(const float4*)&JD[c * 68 + ty * 4];
      float av[4] = {aq.x, aq.y, aq.z, aq.w};
      float bv[4] = {bj.x, bj.y, bj.z, bj.w};
#pragma unroll
      for (int i = 0; i < 4; ++i)
#pragma unroll
        for (int jj = 0; jj < 4; ++jj) acc[i][jj] += av[i] * bv[jj];
    }
    __syncthreads();

    float4 xxjv = *(const float4*)&xxj[ty * 4];
    float xjv[4] = {xxjv.x, xxjv.y, xxjv.z, xxjv.w};
    int selbase = q0 + tx * 4 - jb - ty * 4;
    float d4[4][4];
#pragma unroll
    for (int i = 0; i < 4; ++i) {
      float xq = xxq[tx * 4 + i];
#pragma unroll
      for (int jj = 0; jj < 4; ++jj) {
        float dv = xq - 2.f * acc[i][jj] + xjv[jj];
        d4[i][jj] = (selbase + i == jj) ? 3.4e38f : dv;
      }
    }
#pragma unroll
    for (int jj = 0; jj < 4; ++jj) {
      float4 sv = make_float4(d4[0][jj], d4[1][jj], d4[2][jj], d4[3][jj]);
      *(float4*)&JD[(ty * 4 + jj) * 68 + tx * 4] = sv;
    }
    __syncthreads();

#pragma unroll 4
    for (int jj = 0; jj < 16; ++jj) {
      int jl = quarter * 16 + jj;
      float dv = JD[jl * 68 + sq];
      unsigned long long key = pack_key(dv, (unsigned int)(jb + jl));
      if (key < best[K - 1]) topk_u64(best, key);
    }
  }
  __syncthreads();
  unsigned long long* mb = (unsigned long long*)smem;
#pragma unroll
  for (int k = 0; k < K; ++k) mb[(sq * 4 + quarter) * K + k] = best[k];
  __syncthreads();
  if (t < 64 && q0 + t < N) {
    unsigned long long fb[K];
#pragma unroll
    for (int k = 0; k < K; ++k) fb[k] = KEY_MAX;
    for (int s = 0; s < 4; ++s)
#pragma unroll
      for (int k = 0; k < K; ++k) {
        unsigned long long key = mb[(t * 4 + s) * K + k];
        if (key < fb[K - 1]) topk_u64(fb, key);
      }
    long base = ((long)(b * N + q0 + t) * JS + js) * K;
#pragma unroll
    for (int k = 0; k < K; ++k) pk[base + k] = fb[k];
  }
}

// ---------------- knn merge ----------------
__global__ void __launch_bounds__(256, 4)
knn_merge_kernel(const unsigned long long* __restrict__ pk, int* __restrict__ idx) {
  int t = blockIdx.x * 256 + threadIdx.x;
  if (t >= B * N) return;
  unsigned long long best[K];
#pragma unroll
  for (int k = 0; k < K; ++k) best[k] = KEY_MAX;
  for (int s = 0; s < JS; ++s) {
    long base = ((long)t * JS + s) * K;
#pragma unroll
    for (int k = 0; k < K; ++k) {
      unsigned long long key = pk[base + k];
      if (key < best[K - 1]) topk_u64(best, key);
    }
  }
#pragma unroll
  for (int k = 0; k < K; ++k)
    idx[(long)t * K + k] = (int)(best[k] & 0xFFFFFFFFull);
}

// ---------------- templated tiled SGEMM ----------------
// MODE 0: plain X.  MODE 1: X staged through lrelu(x*scale[c]+shift[c]).
// MODE 2: X = lrelu(scale[c]*(ync[b][c][idx[m]] + ync[b][64+c][m/K]) + shift[c]).
// (256,4): measured VGPR is ~56 under the old (256,2) cap; 128-cap leaves codegen
// unchanged while doubling resident blocks (R10 lesson: these loops are
// occupancy-bound, not LDS-BW-bound).
template<int MODE>
__global__ void __launch_bounds__(256, 4)
gemm_t_kernel(const float* __restrict__ W, int Wld,
              const float* __restrict__ X, long xbstride,
              const int* __restrict__ idx,
              const float* __restrict__ scale, const float* __restrict__ shift,
              float* __restrict__ Y, const float* __restrict__ bias,
              int Co, int Cin, int M) {
  __shared__ __align__(16) float Wt[16][64];
  __shared__ __align__(16) float Xt[16][128];
  __shared__ int jn_s[128];
  __shared__ int nn_s[128];
  int b = blockIdx.z;
  int m0 = blockIdx.x * 128;
  int o0 = blockIdx.y * 64;
  int t = threadIdx.x;
  int tx = t & 15, ty = t >> 4;
  if constexpr (MODE == 2) {
    if (t < 128) {
      int m = m0 + t;
      int n = 0, j = 0;
      if (m < M) { n = m / K; j = idx[(long)b * N * K + m]; }
      nn_s[t] = n; jn_s[t] = j;
    }
    __syncthreads();
  }
  float acc[4][8] = {};
  for (int c0 = 0; c0 < Cin; c0 += 16) {
#pragma unroll
    for (int r = 0; r < 4; ++r) {
      int e = t + r * 256;
      int o = e & 63, kc = e >> 6;
      int oo = o0 + o, cc = c0 + kc;
      Wt[kc][o] = (oo < Co && cc < Cin) ? W[(long)oo * Wld + cc] : 0.f;
    }
    {
      int kc = t >> 4, ms = (t & 15) * 8;
      int cc = c0 + kc;
      int mm = m0 + ms;
      float xv[8];
      if constexpr (MODE == 2) {
        const float* ynr = X + ((long)b * 128 + cc) * N;
        const float* ycr = X + ((long)b * 128 + 64 + cc) * N;
        float sc = scale[cc], sh = shift[cc];
#pragma unroll
        for (int r = 0; r < 8; ++r) {
          int m = mm + r;
          float v = 0.f;
          if (m < M) {
            v = ynr[jn_s[ms + r]] + ycr[nn_s[ms + r]];
            v = v * sc + sh;
            v = v >= 0.f ? v : NEG * v;
          }
          xv[r] = v;
        }
      } else {
        bool okc = cc < Cin;
        const float* Xr = X + (long)b * xbstride + (long)cc * M;
        if (okc && mm + 8 <= M) {
          float4 a0 = *(const float4*)&Xr[mm];
          float4 a1 = *(const float4*)&Xr[mm + 4];
          xv[0] = a0.x; xv[1] = a0.y; xv[2] = a0.z; xv[3] = a0.w;
          xv[4] = a1.x; xv[5] = a1.y; xv[6] = a1.z; xv[7] = a1.w;
        } else {
#pragma unroll
          for (int r = 0; r < 8; ++r)
            xv[r] = (okc && mm + r < M) ? Xr[mm + r] : 0.f;
        }
        if constexpr (MODE == 1) {
          float sc = okc ? scale[cc] : 0.f;
          float sh = okc ? shift[cc] : 0.f;
#pragma unroll
          for (int r = 0; r < 8; ++r) {
            float v = xv[r] * sc + sh;
            xv[r] = v >= 0.f ? v : NEG * v;
          }
        }
      }
      *(float4*)&Xt[kc][ms] = make_float4(xv[0], xv[1], xv[2], xv[3]);
      *(float4*)&Xt[kc][ms + 4] = make_float4(xv[4], xv[5], xv[6], xv[7]);
    }
    __syncthreads();
#pragma unroll
    for (int kc = 0; kc < 16; ++kc) {
      float4 a = *(const float4*)&Wt[kc][ty * 4];
      float4 x0 = *(const float4*)&Xt[kc][tx * 4];
      float4 x1 = *(const float4*)&Xt[kc][64 + tx * 4];
      float av[4] = {a.x, a.y, a.z, a.w};
      float xr[8] = {x0.x, x0.y, x0.z, x0.w, x1.x, x1.y, x1.z, x1.w};
#pragma unroll
      for (int i = 0; i < 4; ++i)
#pragma unroll
        for (int j = 0; j < 8; ++j) acc[i][j] += av[i] * xr[j];
    }
    __syncthreads();
  }
#pragma unroll
  for (int i = 0; i < 4; ++i) {
    int oo = o0 + ty * 4 + i;
    if (oo >= Co) continue;
    float bv = bias ? bias[b * Co + oo] : 0.f;
    long ybase = ((long)b * Co + oo) * M;
    int mlo = m0 + tx * 4, mhi = m0 + 64 + tx * 4;
    if (mlo + 4 <= M) {
      float4 v = make_float4(acc[i][0] + bv, acc[i][1] + bv,
                             acc[i][2] + bv, acc[i][3] + bv);
      *(float4*)&Y[ybase + mlo] = v;
    } else {
#pragma unroll
      for (int j = 0; j < 4; ++j)
        if (mlo + j < M) Y[ybase + mlo + j] = acc[i][j] + bv;
    }
    if (mhi + 4 <= M) {
      float4 v = make_float4(acc[i][4] + bv, acc[i][5] + bv,
                             acc[i][6] + bv, acc[i][7] + bv);
      *(float4*)&Y[ybase + mhi] = v;
    } else {
#pragma unroll
      for (int j = 0; j < 4; ++j)
        if (mhi + j < M) Y[ybase + mhi + j] = acc[i][j + 4] + bv;
    }
  }
}

// ---------------- wcomb[o][c]: rows 0..63 = W_L, rows 64..127 = W_R - W_L ----------------
__global__ void wcomb_kernel(const float* __restrict__ W, int Wld, int Cin,
                             float* __restrict__ wcomb) {
  int e = blockIdx.x * 256 + threadIdx.x;
  if (e < 128 * Cin) {
    int o = e / Cin, c = e % Cin;
    wcomb[e] = (o < 64) ? W[o * Wld + c]
                        : (W[(o - 64) * Wld + Cin + c] - W[(o - 64) * Wld + c]);
  }
}

// ---------------- stats over materialized tensor ----------------
__global__ void __launch_bounds__(256, 4)
stats_kernel(const float* __restrict__ X, int C, int M,
             float* __restrict__ psum, float* __restrict__ psq) {
  int c = blockIdx.x, s = blockIdx.y;
  float sum = 0.f, sq = 0.f;
  for (int b = 0; b < B; ++b) {
    const float* p = X + ((long)b * C + c) * M;
    for (int m = s * 256 + threadIdx.x; m < M; m += SB * 256) {
      float v = p[m];
      sum += v; sq += v * v;
    }
  }
#pragma unroll
  for (int off = 32; off; off >>= 1) {
    sum += __shfl_down(sum, off);
    sq += __shfl_down(sq, off);
  }
  __shared__ float ls[8];
  int wid = threadIdx.x >> 6;
  if ((threadIdx.x & 63) == 0) { ls[wid] = sum; ls[4 + wid] = sq; }
  __syncthreads();
  if (threadIdx.x == 0) {
    psum[c * SB + s] = ls[0] + ls[1] + ls[2] + ls[3];
    psq[c * SB + s] = ls[4] + ls[5] + ls[6] + ls[7];
  }
}

// ---------------- stats over gathered edge tensor (combined ync buffer) ----------------
__global__ void __launch_bounds__(256, 4)
stats_g_kernel(const float* __restrict__ ync, const int* __restrict__ idx,
               float* __restrict__ psum, float* __restrict__ psq) {
  int c = blockIdx.x, s = blockIdx.y;
  float sum = 0.f, sq = 0.f;
  for (int b = 0; b < B; ++b) {
    const float* ynr = ync + ((long)b * 128 + c) * N;
    const float* ycr = ync + ((long)b * 128 + 64 + c) * N;
    const int* ib = idx + (long)b * N * K;
    for (int m = s * 256 + threadIdx.x; m < NK; m += SB * 256) {
      int n = m / K;
      float v = ynr[ib[m]] + ycr[n];
      sum += v; sq += v * v;
    }
  }
#pragma unroll
  for (int off = 32; off; off >>= 1) {
    sum += __shfl_down(sum, off);
    sq += __shfl_down(sq, off);
  }
  __shared__ float ls[8];
  int wid = threadIdx.x >> 6;
  if ((threadIdx.x & 63) == 0) { ls[wid] = sum; ls[4 + wid] = sq; }
  __syncthreads();
  if (threadIdx.x == 0) {
    psum[c * SB + s] = ls[0] + ls[1] + ls[2] + ls[3];
    psq[c * SB + s] = ls[4] + ls[5] + ls[6] + ls[7];
  }
}

__global__ void finalize_kernel(const float* __restrict__ psum, const float* __restrict__ psq,
                                const float* __restrict__ g, const float* __restrict__ bb,
                                float* __restrict__ scale, float* __restrict__ shift,
                                int C, float inv_n) {
  int c = blockIdx.x * 256 + threadIdx.x;
  if (c >= C) return;
  float s = 0.f, q = 0.f;
  for (int i = 0; i < SB; ++i) { s += psum[c * SB + i]; q += psq[c * SB + i]; }
  float mean = s * inv_n;
  float var = q * inv_n - mean * mean;
  float sc = g[c] * rsqrtf(var + BN_EPS);
  scale[c] = sc;
  shift[c] = bb[c] - mean * sc;
}

// ---------------- fused norm+lrelu+max-over-K (materialized Z) ----------------
__global__ void __launch_bounds__(256, 4)
norm_maxk_kernel(const float* __restrict__ Z, const float* __restrict__ scale,
                 const float* __restrict__ shift, float* __restrict__ xc, int coff) {
  long e = (long)blockIdx.x * 256 + threadIdx.x;
  if (e >= (long)B * 64 * N) return;
  int n = (int)(e % N);
  long t = e / N;
  int o = (int)(t % 64);
  int b = (int)(t / 64);
  const float* p = Z + (((long)(b * 64 + o) * N) + n) * K;
  float sc = scale[o], sh = shift[o];
  float m = -3.4e38f;
#pragma unroll
  for (int k = 0; k < K; ++k) {
    float v = p[k] * sc + sh;
    v = v >= 0.f ? v : NEG * v;
    m = fmaxf(m, v);
  }
  xc[((long)b * 192 + coff + o) * N + n] = m;
}

// ---------------- fused gather+norm+lrelu+max-over-K (combined ync) ----------------
__global__ void __launch_bounds__(256, 4)
norm_maxk_g_kernel(const float* __restrict__ ync, const int* __restrict__ idx,
                   const float* __restrict__ scale, const float* __restrict__ shift,
                   float* __restrict__ xc, int coff) {
  long e = (long)blockIdx.x * 256 + threadIdx.x;
  if (e >= (long)B * 64 * N) return;
  int n = (int)(e % N);
  long t = e / N;
  int o = (int)(t % 64);
  int b = (int)(t / 64);
  const int* ib = idx + ((long)b * N + n) * K;
  const float* ynr = ync + ((long)b * 128 + o) * N;
  float ycv = ync[((long)b * 128 + 64 + o) * N + n];
  float sc = scale[o], sh = shift[o];
  float m = -3.4e38f;
#pragma unroll
  for (int k = 0; k < K; ++k) {
    float v = (ynr[ib[k]] + ycv) * sc + sh;
    v = v >= 0.f ? v : NEG * v;
    m = fmaxf(m, v);
  }
  xc[((long)b * 192 + coff + o) * N + n] = m;
}

// ---------------- fused norm+lrelu+max over N (z5 -> glob[0:1024]) ----------------
__global__ void __launch_bounds__(256, 4)
norm_gmax_kernel(const float* __restrict__ Z5, const float* __restrict__ scale,
                 const float* __restrict__ shift, float* __restrict__ glob) {
  int r = blockIdx.x;  // B*1024
  int b = r >> 10, o = r & 1023;
  const float* p = Z5 + (long)r * N;
  float sc = scale[o], sh = shift[o];
  float m = -3.4e38f;
  for (int n = threadIdx.x; n < N; n += 256) {
    float v = p[n] * sc + sh;
    v = v >= 0.f ? v : NEG * v;
    m = fmaxf(m, v);
  }
#pragma unroll
  for (int off = 32; off; off >>= 1) m = fmaxf(m, __shfl_down(m, off));
  __shared__ float ls[4];
  int wid = threadIdx.x >> 6;
  if ((threadIdx.x & 63) == 0) ls[wid] = m;
  __syncthreads();
  if (threadIdx.x == 0)
    glob[b * 1088 + o] = fmaxf(fmaxf(ls[0], ls[1]), fmaxf(ls[2], ls[3]));
}

// ---------------- label branch (tiny) ----------------
__global__ void lfeat_kernel(const float* __restrict__ label, const float* __restrict__ W6,
                             const float* __restrict__ g6, const float* __restrict__ b6,
                             float* __restrict__ glob) {
  int o = threadIdx.x;
  if (o >= 64) return;
  float v[B];
  for (int b = 0; b < B; ++b) {
    float s = 0.f;
    for (int c = 0; c < 16; ++c) s += W6[o * 16 + c] * label[b * 16 + c];
    v[b] = s;
  }
  float mean = 0.f;
  for (int b = 0; b < B; ++b) mean += v[b];
  mean *= (1.f / B);
  float var = 0.f;
  for (int b = 0; b < B; ++b) var += (v[b] - mean) * (v[b] - mean);
  var *= (1.f / B);
  float sc = g6[o] * rsqrtf(var + BN_EPS);
  for (int b = 0; b < B; ++b) {
    float t = (v[b] - mean) * sc + b6[o];
    glob[b * 1088 + 1024 + o] = t >= 0.f ? t : NEG * t;
  }
}

// ---------------- bias0[b][o] = sum_c P0[o][192+c] * glob[b][c] ----------------
__global__ void __launch_bounds__(256, 4)
bias0_kernel(const float* __restrict__ P0, const float* __restrict__ glob,
             float* __restrict__ bias0) {
  int t = blockIdx.x * 256 + threadIdx.x;
  if (t >= B * 256) return;
  int b = t >> 8, o = t & 255;
  float s = 0.f;
  for (int c = 0; c < 1088; ++c) s += P0[o * 1280 + 192 + c] * glob[b * 1088 + c];
  bias0[b * 256 + o] = s;
}

extern "C" void kernel_launch(void* const* d_in, const int* in_sizes, int n_in,
                              void* d_out, int out_size, void* d_ws, size_t ws_size,
                              hipStream_t stream) {
  const float* pts = (const float*)d_in[0];
  const float* label = (const float*)d_in[1];
  const float* Wt7[7]; const float* gt[7]; const float* bt[7];
  for (int i = 0; i < 7; ++i) {
    Wt7[i] = (const float*)d_in[2 + 3 * i];
    gt[i] = (const float*)d_in[3 + 3 * i];
    bt[i] = (const float*)d_in[4 + 3 * i];
  }
  const float* P0 = (const float*)d_in[23];
  const float* P1 = (const float*)d_in[24];
  const float* P2 = (const float*)d_in[25];
  const float* P3 = (const float*)d_in[26];
  const float* pg0 = (const float*)d_in[27]; const float* pb0 = (const float*)d_in[28];
  const float* pg1 = (const float*)d_in[29]; const float* pb1 = (const float*)d_in[30];
  const float* pg2 = (const float*)d_in[31]; const float* pb2 = (const float*)d_in[32];
  float* out = (float*)d_out;

  float* w = (float*)d_ws;
  float* xx = w;                       // 20000
  int* idx = (int*)(w + 20000);        // 200000 ints
  float* ync = w + 220000;             // combined edge buffer [B][128][N] = 2,560,000
  float* wcomb = ync + 2560000;        // 8192
  float* zA = wcomb + 8192;            // 12,800,000
  float* zB = zA + 12800000;           // 12,800,000
  float* xc = zB + 12800000;           // 3,840,000
  float* z5 = xc + 3840000;            // 20,480,000
  float* glob = z5 + 20480000;         // 2176
  float* bias0 = glob + 2176;          // 512
  float* psum = bias0 + 512;           // 65536
  float* psq = psum + 65536;           // 65536
  float* scale = psq + 65536;          // 1024
  float* shift = scale + 1024;         // 1024
  float* hA = zA;                      // head aliases (after knn use)
  float* hB = zB;
  unsigned long long* pk = (unsigned long long*)zA;  // knn scratch, 12.8 MB

  const long xcbs = (long)192 * N;
  const int qblocks = (N + 255) / 256;
  const int qtiles = (N + 63) / 64;

  auto gemm = [&](const float* W, int Wld, const float* X, long xbs, float* Y,
                  const float* bias, int Co, int Cin, int M) {
    dim3 g((M + 127) / 128, (Co + 63) / 64, B);
    gemm_t_kernel<0><<<g, 256, 0, stream>>>(W, Wld, X, xbs, nullptr,
                                            nullptr, nullptr, Y, bias, Co, Cin, M);
  };
  auto gemm_n = [&](const float* W, int Wld, const float* X, long xbs, float* Y,
                    int Co, int Cin, int M) {
    dim3 g((M + 127) / 128, (Co + 63) / 64, B);
    gemm_t_kernel<1><<<g, 256, 0, stream>>>(W, Wld, X, xbs, nullptr,
                                            scale, shift, Y, nullptr, Co, Cin, M);
  };
  auto gemm_gn = [&](const float* W, int Wld, float* Y) {
    dim3 g((NK + 127) / 128, 1, B);
    gemm_t_kernel<2><<<g, 256, 0, stream>>>(W, Wld, ync, 0, idx,
                                            scale, shift, Y, nullptr, 64, 64, NK);
  };
  auto finalize = [&](const float* g, const float* bb, int C, float inv_n) {
    finalize_kernel<<<(C + 255) / 256, 256, 0, stream>>>(psum, psq, g, bb, scale,
                                                         shift, C, inv_n);
  };
  auto stats = [&](const float* Z, int C, int M) {
    stats_kernel<<<dim3(C, SB), 256, 0, stream>>>(Z, C, M, psum, psq);
  };
  auto knn3 = [&](const float* X, long bstride) {
    xx_kernel<<<dim3(qblocks, B), 256, 0, stream>>>(X, bstride, 3, xx);
    knn_partial_kernel<3, 256, 4><<<dim3(qblocks, JS, B), 256, 0, stream>>>(X, bstride, xx, pk);
    knn_merge_kernel<<<(B * N + 255) / 256, 256, 0, stream>>>(pk, idx);
  };
  auto knn64 = [&](const float* X, long bstride) {
    xx_kernel<<<dim3(qblocks, B), 256, 0, stream>>>(X, bstride, 64, xx);
    knn64_tiled_kernel<<<dim3(qtiles, JS, B), 256, 0, stream>>>(X, bstride, xx, pk);
    knn_merge_kernel<<<(B * N + 255) / 256, 256, 0, stream>>>(pk, idx);
  };
  auto edge_pre = [&](const float* Wconv, int Wld, int Cin, const float* X, long xbs,
                      const float* g, const float* bb) {
    // ync[b][0:64] = W_L @ x ; ync[b][64:128] = (W_R - W_L) @ x  (one Co=128 gemm)
    wcomb_kernel<<<(128 * Cin + 255) / 256, 256, 0, stream>>>(Wconv, Wld, Cin, wcomb);
    gemm(wcomb, Cin, X, xbs, ync, nullptr, 128, Cin, N);
    stats_g_kernel<<<dim3(64, SB), 256, 0, stream>>>(ync, idx, psum, psq);
    finalize(g, bb, 64, 1.f / (float)(B * NK));
  };
  const int mk_blocks = (int)(((long)B * 64 * N + 255) / 256);

  // ---- Stage 1 ----
  knn3(pts, (long)3 * N);
  edge_pre(Wt7[0], 6, 3, pts, (long)3 * N, gt[0], bt[0]);
  gemm_gn(Wt7[1], 64, zB);
  stats(zB, 64, NK);
  finalize(gt[1], bt[1], 64, 1.f / (float)(B * NK));
  norm_maxk_kernel<<<mk_blocks, 256, 0, stream>>>(zB, scale, shift, xc, 0);

  // ---- Stage 2 ----
  const float* x1 = xc;
  knn64(x1, xcbs);
  edge_pre(Wt7[2], 128, 64, x1, xcbs, gt[2], bt[2]);
  gemm_gn(Wt7[3], 64, zB);
  stats(zB, 64, NK);
  finalize(gt[3], bt[3], 64, 1.f / (float)(B * NK));
  norm_maxk_kernel<<<mk_blocks, 256, 0, stream>>>(zB, scale, shift, xc, 64);

  // ---- Stage 3 (edge tensor never materialized) ----
  const float* x2 = xc + (long)64 * N;
  knn64(x2, xcbs);
  edge_pre(Wt7[4], 128, 64, x2, xcbs, gt[4], bt[4]);
  norm_maxk_g_kernel<<<mk_blocks, 256, 0, stream>>>(ync, idx, scale, shift, xc, 128);

  // ---- Stage 4: global feature ----
  gemm(Wt7[5], 192, xc, xcbs, z5, nullptr, 1024, 192, N);
  stats(z5, 1024, N);
  finalize(gt[5], bt[5], 1024, 1.f / (float)(B * N));
  norm_gmax_kernel<<<B * 1024, 256, 0, stream>>>(z5, scale, shift, glob);
  lfeat_kernel<<<1, 64, 0, stream>>>(label, Wt7[6], gt[6], bt[6], glob);
  bias0_kernel<<<2, 256, 0, stream>>>(P0, glob, bias0);

  // ---- Stage 5: point head (norm fused into consumer staging) ----
  gemm(P0, 1280, xc, xcbs, hA, bias0, 256, 192, N);
  stats(hA, 256, N);
  finalize(pg0, pb0, 256, 1.f / (float)(B * N));
  gemm_n(P1, 256, hA, (long)256 * N, hB, 256, 256, N);
  stats(hB, 256, N);
  finalize(pg1, pb1, 256, 1.f / (float)(B * N));
  gemm_n(P2, 256, hB, (long)256 * N, hA, 128, 256, N);
  stats(hA, 128, N);
  finalize(pg2, pb2, 128, 1.f / (float)(B * N));
  gemm_n(P3, 128, hA, (long)128 * N, out, 6, 128, N);
}